// Round 1
// baseline (935.954 us; speedup 1.0000x reference)
//
#include <hip/hip_runtime.h>
#include <stdint.h>

// TT-stack: out[b][(a,c,d)][(i,j,l)] = sum_{k,m} c0[s][a,i,k] c1[s][k,c,j,m] c2[s][m,d,l]
// One block per b (512 blocks x 512 threads). c1 staged ONCE per b (was 8x).
// Step1 (VALU, fp32 c0 x bf16 c1 -> t bf16) ; Step2 on MFMA 16x16x32_bf16 with
// c2 split hi+lo bf16 folded into the K=32 axis (K 0-15 = c2_hi, 16-31 = c2_lo,
// t duplicated) -> numerics == fp32 c2 path. t rows are WAVE-PRIVATE in LDS
// (rows wv*64..wv*64+63), DS ops are in-order per wave => NO barrier in a-loop.
// LDS 56KB -> 2 blocks/CU (16 waves/CU). Single __syncthreads after staging.

typedef short short8 __attribute__((ext_vector_type(8)));
typedef float f32x4 __attribute__((ext_vector_type(4)));

__device__ __forceinline__ float bflo(uint32_t u) { return __uint_as_float(u << 16); }
__device__ __forceinline__ float bfhi(uint32_t u) { return __uint_as_float(u & 0xffff0000u); }
__device__ __forceinline__ uint32_t pack_bf2(float f0, float f1) {
  uint32_t a = __float_as_uint(f0) + 0x8000u;
  uint32_t b = __float_as_uint(f1) + 0x8000u;
  return (a >> 16) | (b & 0xffff0000u);
}

__global__ __launch_bounds__(512, 4) void tt_stack_kernel(
    const float* __restrict__ c0f,
    const float* __restrict__ c1f,
    const float* __restrict__ c2f,
    const int* __restrict__ idx,
    float* __restrict__ outf)
{
  __shared__ __align__(16) uint32_t lds_c1[8192];   // bf16 pairs [k][c][j][m/2]  32 KB
  __shared__ __align__(16) float    lds_c0[1024];   // fp32 [a][i][k]              4 KB
  __shared__ __align__(16) uint32_t lds_c2b[1024];  // bf16 [col=(d,l)][kk=32]     4 KB
  __shared__ __align__(16) uint32_t lds_t[4096];    // bf16 [row=512][m=16] swz   16 KB

  const int tid = threadIdx.x;
  const int b = blockIdx.x;
  const int s = idx[b];
  const size_t s1024 = (size_t)s * 1024;

  // ---- stage: c1 (coalesced float4 -> bf16 pairs), c0 fp32, c2 -> hi/lo bf16 ----
  {
    const float4* src4 = (const float4*)(c1f + (size_t)s * 16384);
    float4 cv[8];
#pragma unroll
    for (int it = 0; it < 8; ++it) cv[it] = src4[it * 512 + tid];
    const float g0 = c0f[s1024 + tid];
    const float g1 = c0f[s1024 + 512 + tid];
    const int w = tid & 7;        // m-pair index (m = 2w, 2w+1)
    const int col = tid >> 3;     // (d,l) column 0..63
    const float v0 = c2f[s1024 + (size_t)(2 * w) * 64 + col];
    const float v1 = c2f[s1024 + (size_t)(2 * w + 1) * 64 + col];
#pragma unroll
    for (int it = 0; it < 8; ++it) {
      uint2* dst = (uint2*)&lds_c1[2 * (it * 512 + tid)];
      *dst = make_uint2(pack_bf2(cv[it].x, cv[it].y), pack_bf2(cv[it].z, cv[it].w));
    }
    lds_c0[tid] = g0;
    lds_c0[512 + tid] = g1;
    // c2 hi = bf16(v), lo = bf16(v - hi): hi occupies kk = m (words 0..7),
    // lo occupies kk = 16+m (words 8..15) of each column's 32-wide K axis.
    const uint32_t h0 = (__float_as_uint(v0) + 0x8000u) & 0xffff0000u;
    const uint32_t h1 = (__float_as_uint(v1) + 0x8000u) & 0xffff0000u;
    lds_c2b[col * 16 + w] = (h0 >> 16) | h1;
    lds_c2b[col * 16 + 8 + w] =
        pack_bf2(v0 - __uint_as_float(h0), v1 - __uint_as_float(h1));
  }
  __syncthreads();  // the only barrier

  const int lane = tid & 63, wv = tid >> 6;
  const int g = lane >> 4, lcol = lane & 15;

  // B-fragments (c2 hi|lo over kk=32), one per 16-col tile; live in 16 VGPRs.
  short8 Bfr[4];
#pragma unroll
  for (int ct = 0; ct < 4; ++ct)
    Bfr[ct] = *(const short8*)&lds_c2b[(ct * 16 + lcol) * 16 + g * 4];

  const int c = tid >> 6, i = (tid >> 3) & 7, j = tid & 7;
  const int sw = (tid >> 2) & 1;                 // t-row half swizzle (write side)
  const int hsel = (g & 1) ^ ((lcol >> 2) & 1);  // t-row half swizzle (read side)
  float* const outb = outf + (size_t)b * 262144;

  for (int a = 0; a < 8; ++a) {
    // ---- step 1: t[row=(c,i,j)][m] = sum_k c0[a,i,k] * c1[k,c,j,m]  (VALU) ----
    float a_k[16];
    {
      const float4* c0p = (const float4*)&lds_c0[a * 128 + i * 16];
#pragma unroll
      for (int q = 0; q < 4; ++q) *(float4*)&a_k[q * 4] = c0p[q];
    }
    float acc[16];
#pragma unroll
    for (int m = 0; m < 16; ++m) acc[m] = 0.f;
#pragma unroll
    for (int k = 0; k < 16; ++k) {
      const uint4* rp = (const uint4*)&lds_c1[((k * 8 + c) * 8 + j) * 8];
      const uint4 u0 = rp[0];
      const uint4 u1 = rp[1];
      const float av = a_k[k];
      acc[0]  = fmaf(av, bflo(u0.x), acc[0]);   acc[1]  = fmaf(av, bfhi(u0.x), acc[1]);
      acc[2]  = fmaf(av, bflo(u0.y), acc[2]);   acc[3]  = fmaf(av, bfhi(u0.y), acc[3]);
      acc[4]  = fmaf(av, bflo(u0.z), acc[4]);   acc[5]  = fmaf(av, bfhi(u0.z), acc[5]);
      acc[6]  = fmaf(av, bflo(u0.w), acc[6]);   acc[7]  = fmaf(av, bfhi(u0.w), acc[7]);
      acc[8]  = fmaf(av, bflo(u1.x), acc[8]);   acc[9]  = fmaf(av, bfhi(u1.x), acc[9]);
      acc[10] = fmaf(av, bflo(u1.y), acc[10]);  acc[11] = fmaf(av, bfhi(u1.y), acc[11]);
      acc[12] = fmaf(av, bflo(u1.z), acc[12]);  acc[13] = fmaf(av, bfhi(u1.z), acc[13]);
      acc[14] = fmaf(av, bflo(u1.w), acc[14]);  acc[15] = fmaf(av, bfhi(u1.w), acc[15]);
    }
    // write own t row (wave-private region), halves XOR-swizzled by (row>>2)&1
    {
      uint32_t* tb = &lds_t[tid * 8];
      *(uint4*)&tb[sw * 4] =
          make_uint4(pack_bf2(acc[0], acc[1]),  pack_bf2(acc[2], acc[3]),
                     pack_bf2(acc[4], acc[5]),  pack_bf2(acc[6], acc[7]));
      *(uint4*)&tb[4 - sw * 4] =
          make_uint4(pack_bf2(acc[8], acc[9]),  pack_bf2(acc[10], acc[11]),
                     pack_bf2(acc[12], acc[13]), pack_bf2(acc[14], acc[15]));
    }

    // ---- step 2: out-tile = t-tile @ c2  via mfma_f32_16x16x32_bf16 ----
    // A lane(row=lcol) reads its m-half (g&1) of t row; kk labeling matches Bfr.
    float* const oa = outb + a * 32768;
#pragma unroll
    for (int rt4 = 0; rt4 < 4; ++rt4) {
      const int rt = wv * 4 + rt4;            // row-tile 0..31 (wave-private rows)
      const int row = rt * 16 + lcol;
      const short8 av8 = *(const short8*)&lds_t[row * 8 + hsel * 4];
      const int ii = (rt * 2 + (g >> 1)) & 7; // i of D rows (combo>>3)&7
      float* const ob = oa + (rt >> 2) * 4096 + ii * 64 + (g & 1) * 32;
#pragma unroll
      for (int ct = 0; ct < 4; ++ct) {
        f32x4 dd = {0.f, 0.f, 0.f, 0.f};
        dd = __builtin_amdgcn_mfma_f32_16x16x32_bf16(av8, Bfr[ct], dd, 0, 0, 0);
        const int colx = ct * 16 + lcol;      // (d,l) within 64 cols
        float* p = ob + ((colx >> 3) * 512) + (colx & 7);
        // D: col=lane&15, row=(lane>>4)*4+reg  ->  j = j0 + reg  -> +8 floats/reg
        p[0]  = dd[0];
        p[8]  = dd[1];
        p[16] = dd[2];
        p[24] = dd[3];
      }
    }
    // next a: same wave overwrites its own t rows -> DS in-order, no barrier
  }
}

extern "C" void kernel_launch(void* const* d_in, const int* in_sizes, int n_in,
                              void* d_out, int out_size, void* d_ws, size_t ws_size,
                              hipStream_t stream) {
  const float* c0f = (const float*)d_in[0];
  const float* c1f = (const float*)d_in[1];
  const float* c2f = (const float*)d_in[2];
  const int* idx = (const int*)d_in[3];
  float* outf = (float*)d_out;
  const int B = in_sizes[3];  // 512
  dim3 grid(B), block(512);
  hipLaunchKernelGGL(tt_stack_kernel, grid, block, 0, stream, c0f, c1f, c2f, idx, outf);
}